// Round 1
// baseline (826.522 us; speedup 1.0000x reference)
//
#include <hip/hip_runtime.h>

// Problem constants (N=1)
constexpr int W_ = 160;   // input W (x), output dim 1
constexpr int H_ = 192;   // input H (y), output dim 2
constexpr int D_ = 64;    // input D (z), output dim 4 (innermost)
constexpr int C_ = 32;
constexpr int HW_  = H_ * W_;          // 30720
constexpr int DHW  = D_ * H_ * W_;     // 1966080

// Block: 256 threads = 64 w-lanes x 4 waves (each wave owns 4 of the 16 d's in the tile).
// Grid: 3 w-tiles x 192 h x 4 d-tiles = 2304 blocks.
// Per block: gather (lanes along w for input-x locality) -> LDS -> coalesced float4
// stores along d (output-innermost).
__global__ void __launch_bounds__(256)
affine_grid_sample_kernel(const float* __restrict__ inp,
                          const float* __restrict__ th,
                          float* __restrict__ out)
{
    // layout: lds[w*129 + d_local*8 + c_local]; stride 129 breaks bank aliasing
    __shared__ float lds[64 * 129];

    const int t    = threadIdx.x;
    const int lane = t & 63;
    const int sub  = t >> 6;          // wave id 0..3

    int bid = blockIdx.x;
    const int wt = bid % 3; bid /= 3;     // w-tile 0..2
    const int h  = bid % H_; bid /= H_;   // 0..191
    const int dt = bid;                    // d-tile 0..3
    const int w0 = wt << 6;
    const int d0 = dt << 4;
    const int w  = w0 + lane;

    // theta: uniform scalar loads
    const float th0 = th[0], th1 = th[1], th2  = th[2],  th3  = th[3];
    const float th4 = th[4], th5 = th[5], th6  = th[6],  th7  = th[7];
    const float th8 = th[8], th9 = th[9], th10 = th[10], th11 = th[11];

    const float xx = fmaf((float)w, 2.0f / (W_ - 1), -1.0f);
    const float yy = fmaf((float)h, 2.0f / (H_ - 1), -1.0f);

    // Per-(lane,d) precompute: 8 corner element-offsets + 6 axis weights,
    // reused across all 32 channels.
    unsigned offs[4][8];
    float u0a[4], u1a[4], v0a[4], v1a[4], s0a[4], s1a[4];

    #pragma unroll
    for (int k = 0; k < 4; ++k) {
        const int d = d0 + (sub << 2) + k;
        const float zz = fmaf((float)d, 2.0f / (D_ - 1), -1.0f);
        const float gx = fmaf(th0, xx, fmaf(th1, yy, fmaf(th2,  zz, th3)));
        const float gy = fmaf(th4, xx, fmaf(th5, yy, fmaf(th6,  zz, th7)));
        const float gz = fmaf(th8, xx, fmaf(th9, yy, fmaf(th10, zz, th11)));
        const float px = (gx + 1.0f) * (0.5f * (W_ - 1));
        const float py = (gy + 1.0f) * (0.5f * (H_ - 1));
        const float pz = (gz + 1.0f) * (0.5f * (D_ - 1));
        const float fx = floorf(px), fy = floorf(py), fz = floorf(pz);
        const int ix0 = (int)fx, iy0 = (int)fy, iz0 = (int)fz;
        const int ix1 = ix0 + 1, iy1 = iy0 + 1, iz1 = iz0 + 1;
        const float wx = px - fx, wy = py - fy, wz = pz - fz;
        // zeros-padding: zero the per-axis weight of any out-of-range corner
        u0a[k] = (ix0 >= 0 && ix0 < W_) ? (1.0f - wx) : 0.0f;
        u1a[k] = (ix1 >= 0 && ix1 < W_) ? wx          : 0.0f;
        v0a[k] = (iy0 >= 0 && iy0 < H_) ? (1.0f - wy) : 0.0f;
        v1a[k] = (iy1 >= 0 && iy1 < H_) ? wy          : 0.0f;
        s0a[k] = (iz0 >= 0 && iz0 < D_) ? (1.0f - wz) : 0.0f;
        s1a[k] = (iz1 >= 0 && iz1 < D_) ? wz          : 0.0f;
        const int cx0 = min(max(ix0, 0), W_ - 1), cx1 = min(max(ix1, 0), W_ - 1);
        const int cy0 = min(max(iy0, 0), H_ - 1), cy1 = min(max(iy1, 0), H_ - 1);
        const int cz0 = min(max(iz0, 0), D_ - 1), cz1 = min(max(iz1, 0), D_ - 1);
        const unsigned o00 = (unsigned)(cz0 * HW_ + cy0 * W_);
        const unsigned o01 = (unsigned)(cz0 * HW_ + cy1 * W_);
        const unsigned o10 = (unsigned)(cz1 * HW_ + cy0 * W_);
        const unsigned o11 = (unsigned)(cz1 * HW_ + cy1 * W_);
        // predicate off the w-padding lanes (last w-tile covers w 128..191):
        // offset 0 -> all idle lanes hit one line, results never read back
        const unsigned mask = (w < W_) ? 0xFFFFFFFFu : 0u;
        offs[k][0] = (o00 + (unsigned)cx0) & mask;
        offs[k][1] = (o00 + (unsigned)cx1) & mask;
        offs[k][2] = (o01 + (unsigned)cx0) & mask;
        offs[k][3] = (o01 + (unsigned)cx1) & mask;
        offs[k][4] = (o10 + (unsigned)cx0) & mask;
        offs[k][5] = (o10 + (unsigned)cx1) & mask;
        offs[k][6] = (o11 + (unsigned)cx0) & mask;
        offs[k][7] = (o11 + (unsigned)cx1) & mask;
    }

    // 4 channel-chunks of 8
    for (int cc = 0; cc < 4; ++cc) {
        // ---- phase 1: gather (lanes along w) into LDS ----
        #pragma unroll
        for (int k = 0; k < 4; ++k) {
            const int ldsb = lane * 129 + ((sub << 2) + k) * 8;
            const float u0 = u0a[k], u1 = u1a[k];
            const float v0 = v0a[k], v1 = v1a[k];
            const float s0 = s0a[k], s1 = s1a[k];
            #pragma unroll
            for (int c = 0; c < 8; ++c) {
                const float* __restrict__ pc = inp + (size_t)(cc * 8 + c) * DHW;
                const float b000 = pc[offs[k][0]];
                const float b001 = pc[offs[k][1]];
                const float b010 = pc[offs[k][2]];
                const float b011 = pc[offs[k][3]];
                const float b100 = pc[offs[k][4]];
                const float b101 = pc[offs[k][5]];
                const float b110 = pc[offs[k][6]];
                const float b111 = pc[offs[k][7]];
                const float r00 = u0 * b000 + u1 * b001;   // x-lerp, z0 y0
                const float r01 = u0 * b010 + u1 * b011;   // x-lerp, z0 y1
                const float r10 = u0 * b100 + u1 * b101;   // x-lerp, z1 y0
                const float r11 = u0 * b110 + u1 * b111;   // x-lerp, z1 y1
                const float rz0 = v0 * r00 + v1 * r01;     // y-lerp, z0
                const float rz1 = v0 * r10 + v1 * r11;     // y-lerp, z1
                lds[ldsb + c] = s0 * rz0 + s1 * rz1;       // z-lerp
            }
        }
        __syncthreads();

        // ---- phase 2: LDS -> global, coalesced float4 along d ----
        {
            const int w2 = t >> 2;      // 0..63
            const int q  = t & 3;       // d-quarter within the 16-d tile
            if (w0 + w2 < W_) {
                const int rb = w2 * 129 + q * 32;
                float* ob = out + ((size_t)(w0 + w2) * H_ + h) * (C_ * D_)
                                + (size_t)(cc * 8) * D_ + d0 + (q << 2);
                #pragma unroll
                for (int c = 0; c < 8; ++c) {
                    float4 v;
                    v.x = lds[rb + 0 * 8 + c];
                    v.y = lds[rb + 1 * 8 + c];
                    v.z = lds[rb + 2 * 8 + c];
                    v.w = lds[rb + 3 * 8 + c];
                    *reinterpret_cast<float4*>(ob + c * D_) = v;
                }
            }
        }
        __syncthreads();
    }
}

extern "C" void kernel_launch(void* const* d_in, const int* in_sizes, int n_in,
                              void* d_out, int out_size, void* d_ws, size_t ws_size,
                              hipStream_t stream)
{
    const float* inp = (const float*)d_in[0];   // [1,32,64,192,160] fp32
    const float* th  = (const float*)d_in[1];   // 12 fp32
    float* out = (float*)d_out;                 // [1,160,192,32,64] fp32

    const int grid = 3 * H_ * 4;  // w-tiles * h * d-tiles = 2304
    hipLaunchKernelGGL(affine_grid_sample_kernel, dim3(grid), dim3(256), 0, stream,
                       inp, th, out);
}

// Round 2
// 766.132 us; speedup vs baseline: 1.0788x; 1.0788x over previous
//
#include <hip/hip_runtime.h>

// Problem constants (N=1)
constexpr int W_ = 160;   // input W (x), output dim 1
constexpr int H_ = 192;   // input H (y), output dim 2
constexpr int D_ = 64;    // input D (z), output dim 4 (innermost)
constexpr int C_ = 32;
constexpr int HW_ = H_ * W_;          // 30720
constexpr int DHW = D_ * H_ * W_;     // 1966080
constexpr int CD  = C_ * D_;          // 2048

typedef float f4_t __attribute__((ext_vector_type(4)));

// Tile: (w:64, h:24, d:16, c:4). Grid = 8 h-slabs x 3 w-tiles x 4 d-tiles x 8 c-chunks
//     = 768 blocks = exactly 3 per CU.
// Swizzle: xcd = bid&7 = h-slab (XCD owns contiguous 24 output rows -> L2/L3 y-locality);
//          dt slowest within each XCD -> z-slab phases globally synchronized (L3 holds
//          one phase's ~60 MB working set, absorbing halo re-reads).
// Fat h-tile amortizes the ~13-row y-halo created by theta's off-diagonal rotation
// (was 13 rows of footprint per 1 output row -> now per 24 rows).
__global__ void __launch_bounds__(256)
affine_grid_sample_kernel(const float* __restrict__ inp,
                          const float* __restrict__ th,
                          float* __restrict__ out)
{
    // lds[w*65 + dl*4 + c]  (dl in 0..15, c in 0..3); stride 65 -> phase-1 writes
    // 2-way (free), phase-2 reads 2-way (free).
    __shared__ float lds[64 * 65];

    const int t    = threadIdx.x;
    const int lane = t & 63;
    const int sub  = t >> 6;          // wave 0..3

    const int bid = blockIdx.x;
    const int xcd = bid & 7;          // h-slab
    int local = bid >> 3;             // 0..95
    const int cs = local & 7;         // c-chunk (fastest)
    local >>= 3;                      // 0..11
    const int wt = local % 3;
    const int dt = local / 3;         // slowest -> phase-synchronized z sweep
    const int h0 = xcd * 24;
    const int w0 = wt << 6;
    const int d0 = dt << 4;
    const int c0 = cs << 2;
    const int w  = w0 + lane;

    const float th0 = th[0], th1 = th[1], th2  = th[2],  th3  = th[3];
    const float th4 = th[4], th5 = th[5], th6  = th[6],  th7  = th[7];
    const float th8 = th[8], th9 = th[9], th10 = th[10], th11 = th[11];

    const float xx = fmaf((float)w, 2.0f / (W_ - 1), -1.0f);
    // predicate off w-padding lanes (last w-tile covers w 128..191): offset 0,
    // values never read back in phase 2
    const unsigned mask = (w < W_) ? 0xFFFFFFFFu : 0u;

    const float* __restrict__ base = inp + (size_t)c0 * DHW;

    #pragma unroll 1
    for (int hl = 0; hl < 24; ++hl) {
        const int h = h0 + hl;
        const float yy = fmaf((float)h, 2.0f / (H_ - 1), -1.0f);

        // per-(lane, d) corner offsets + axis weights for this h; reused across 4 channels
        unsigned offs[4][8];
        float u0a[4], u1a[4], v0a[4], v1a[4], s0a[4], s1a[4];

        #pragma unroll
        for (int k = 0; k < 4; ++k) {
            const int d = d0 + (sub << 2) + k;
            const float zz = fmaf((float)d, 2.0f / (D_ - 1), -1.0f);
            const float gx = fmaf(th0, xx, fmaf(th1, yy, fmaf(th2,  zz, th3)));
            const float gy = fmaf(th4, xx, fmaf(th5, yy, fmaf(th6,  zz, th7)));
            const float gz = fmaf(th8, xx, fmaf(th9, yy, fmaf(th10, zz, th11)));
            const float px = (gx + 1.0f) * (0.5f * (W_ - 1));
            const float py = (gy + 1.0f) * (0.5f * (H_ - 1));
            const float pz = (gz + 1.0f) * (0.5f * (D_ - 1));
            const float fx = floorf(px), fy = floorf(py), fz = floorf(pz);
            const int ix0 = (int)fx, iy0 = (int)fy, iz0 = (int)fz;
            const int ix1 = ix0 + 1, iy1 = iy0 + 1, iz1 = iz0 + 1;
            const float wx = px - fx, wy = py - fy, wz = pz - fz;
            // zeros-padding: zero the per-axis weight of any out-of-range corner
            u0a[k] = (ix0 >= 0 && ix0 < W_) ? (1.0f - wx) : 0.0f;
            u1a[k] = (ix1 >= 0 && ix1 < W_) ? wx          : 0.0f;
            v0a[k] = (iy0 >= 0 && iy0 < H_) ? (1.0f - wy) : 0.0f;
            v1a[k] = (iy1 >= 0 && iy1 < H_) ? wy          : 0.0f;
            s0a[k] = (iz0 >= 0 && iz0 < D_) ? (1.0f - wz) : 0.0f;
            s1a[k] = (iz1 >= 0 && iz1 < D_) ? wz          : 0.0f;
            const int cx0 = min(max(ix0, 0), W_ - 1), cx1 = min(max(ix1, 0), W_ - 1);
            const int cy0 = min(max(iy0, 0), H_ - 1), cy1 = min(max(iy1, 0), H_ - 1);
            const int cz0 = min(max(iz0, 0), D_ - 1), cz1 = min(max(iz1, 0), D_ - 1);
            const unsigned o00 = (unsigned)(cz0 * HW_ + cy0 * W_);
            const unsigned o01 = (unsigned)(cz0 * HW_ + cy1 * W_);
            const unsigned o10 = (unsigned)(cz1 * HW_ + cy0 * W_);
            const unsigned o11 = (unsigned)(cz1 * HW_ + cy1 * W_);
            offs[k][0] = (o00 + (unsigned)cx0) & mask;
            offs[k][1] = (o00 + (unsigned)cx1) & mask;
            offs[k][2] = (o01 + (unsigned)cx0) & mask;
            offs[k][3] = (o01 + (unsigned)cx1) & mask;
            offs[k][4] = (o10 + (unsigned)cx0) & mask;
            offs[k][5] = (o10 + (unsigned)cx1) & mask;
            offs[k][6] = (o11 + (unsigned)cx0) & mask;
            offs[k][7] = (o11 + (unsigned)cx1) & mask;
        }

        // ---- phase 1: gather (lanes along w for input-x locality) -> LDS ----
        #pragma unroll
        for (int k = 0; k < 4; ++k) {
            const int ldsb = lane * 65 + ((sub << 2) + k) * 4;
            const float u0 = u0a[k], u1 = u1a[k];
            const float v0 = v0a[k], v1 = v1a[k];
            const float s0 = s0a[k], s1 = s1a[k];
            #pragma unroll
            for (int c = 0; c < 4; ++c) {
                const float* __restrict__ pc = base + (size_t)c * DHW;
                const float b000 = pc[offs[k][0]];
                const float b001 = pc[offs[k][1]];
                const float b010 = pc[offs[k][2]];
                const float b011 = pc[offs[k][3]];
                const float b100 = pc[offs[k][4]];
                const float b101 = pc[offs[k][5]];
                const float b110 = pc[offs[k][6]];
                const float b111 = pc[offs[k][7]];
                const float r00 = u0 * b000 + u1 * b001;
                const float r01 = u0 * b010 + u1 * b011;
                const float r10 = u0 * b100 + u1 * b101;
                const float r11 = u0 * b110 + u1 * b111;
                const float rz0 = v0 * r00 + v1 * r01;
                const float rz1 = v0 * r10 + v1 * r11;
                lds[ldsb + c] = s0 * rz0 + s1 * rz1;
            }
        }
        __syncthreads();

        // ---- phase 2: LDS -> global, coalesced full-line float4 stores along d ----
        {
            const int w2 = t >> 2;      // 0..63
            const int q  = t & 3;       // d-quarter (4 floats each)
            if (w0 + w2 < W_) {
                const int rb = w2 * 65 + q * 16;
                float* ob = out + ((size_t)(w0 + w2) * H_ + h) * CD
                                + (size_t)c0 * D_ + d0 + (q << 2);
                #pragma unroll
                for (int c = 0; c < 4; ++c) {
                    f4_t v;
                    v.x = lds[rb + 0  + c];
                    v.y = lds[rb + 4  + c];
                    v.z = lds[rb + 8  + c];
                    v.w = lds[rb + 12 + c];
                    // non-temporal: output is write-once streaming; keep it from
                    // evicting input out of L2/L3
                    __builtin_nontemporal_store(v, (f4_t*)(ob + (size_t)c * D_));
                }
            }
        }
        __syncthreads();
    }
}

extern "C" void kernel_launch(void* const* d_in, const int* in_sizes, int n_in,
                              void* d_out, int out_size, void* d_ws, size_t ws_size,
                              hipStream_t stream)
{
    const float* inp = (const float*)d_in[0];   // [1,32,64,192,160] fp32
    const float* th  = (const float*)d_in[1];   // 12 fp32
    float* out = (float*)d_out;                 // [1,160,192,32,64] fp32

    hipLaunchKernelGGL(affine_grid_sample_kernel, dim3(768), dim3(256), 0, stream,
                       inp, th, out);
}